// Round 3
// baseline (384.515 us; speedup 1.0000x reference)
//
// VQ layer (gumbel-softmax VQ) fused pipeline for MI355X (gfx950). Round 3.
//
//   K0a split_w : W_h, W_logits (512x512 f32) -> f16 hi/lo planes in ws
//   K0b split_x : X (65536x512 f32) -> f16 hi/lo planes in ws
//   K1  gemm2<0>: hiddens = relu(X @ Wh^T + bh) -> f16 hi/lo planes in codes half of d_out
//   K2  gemm2<1>: logits = hiddens @ Wl^T + bl -> d_out (f32)
//   K3  argmax  : z = logits + gumbel(u); codes[row,:] = codebook[argmax z,:]
//
// f32-GEMM emulation: a = hi + lo*2^-12 (f16 split, lo scaled by 2^12), using
// 3 MFMAs: hi.hi -> acc_hh ; hi.lo + lo.hi -> acc_mx ; D = acc_hh + acc_mx*2^-12.
//
// GEMM v2: 128x128 tile, 4 waves (64x64 each, 2x2 of 32x32x16 f16 MFMA),
// BK=32, double-buffered LDS (2 x 32KB), 2-phase prefetch pipeline
// (STAGE next before compute cur, one barrier per K-step), XOR-swizzled
// source for global_load_lds (rule 21: linear dest + inverse-swz source +
// same swz on ds_read), XCD-chunked block swizzle.

#include <hip/hip_runtime.h>
#include <hip/hip_fp16.h>

typedef _Float16 h16;
typedef __attribute__((ext_vector_type(8))) _Float16 h16x8;
typedef __attribute__((ext_vector_type(4))) _Float16 h16x4;
typedef __attribute__((ext_vector_type(4))) float f32x4;
typedef __attribute__((ext_vector_type(16))) float f32x16;

#define KDIM 512
#define NDIM 512
#define LO_SCALE 4096.0f
#define LO_INV   0.000244140625f

__device__ __forceinline__ void gload16(const void* g, void* l) {
  __builtin_amdgcn_global_load_lds((const __attribute__((address_space(1))) void*)g,
                                   (__attribute__((address_space(3))) void*)l, 16, 0, 0);
}

// ---------------- K0a: split weights into f16 hi/lo planes ----------------
__global__ void split_w(const float* __restrict__ Wh, const float* __restrict__ Wl,
                        h16* __restrict__ WhHi, h16* __restrict__ WhLo,
                        h16* __restrict__ WlHi, h16* __restrict__ WlLo) {
  int i = blockIdx.x * 256 + threadIdx.x;          // 262144 elements
  float a = Wh[i];
  h16 h = (h16)a;
  WhHi[i] = h; WhLo[i] = (h16)((a - (float)h) * LO_SCALE);
  a = Wl[i];
  h = (h16)a;
  WlHi[i] = h; WlLo[i] = (h16)((a - (float)h) * LO_SCALE);
}

// ---------------- K0b: split inputs into f16 hi/lo planes ----------------
__global__ void split_x(const f32x4* __restrict__ X, h16x4* __restrict__ XHi,
                        h16x4* __restrict__ XLo) {
  int i = blockIdx.x * 256 + threadIdx.x;          // 8388608 f32x4 groups
  f32x4 a = X[i];
  h16x4 hv, lv;
#pragma unroll
  for (int j = 0; j < 4; ++j) {
    h16 h = (h16)a[j];
    hv[j] = h;
    lv[j] = (h16)((a[j] - (float)h) * LO_SCALE);
  }
  XHi[i] = hv; XLo[i] = lv;
}

// =========== GEMM v2: C[m,n] = sum_k A[m,k]*B[n,k] (+bias, epilogue) ======
// EPI 0: relu + split -> OHi/OLo planes (via LDS-packed coalesced store).
// EPI 1: f32 store to Cf32.
template <int EPI>
__launch_bounds__(256, 2)
__global__ void gemm2_k(const h16* __restrict__ AHi, const h16* __restrict__ ALo,
                        const h16* __restrict__ BHi, const h16* __restrict__ BLo,
                        const float* __restrict__ bias,
                        float* __restrict__ Cf32,
                        h16* __restrict__ OHi, h16* __restrict__ OLo) {
  // LDS: 2 buffers x {Ah[128][32] Al Bh[128][32] Bl} x 8KB = 64 KB total.
  __shared__ __align__(16) char lds[65536];
  const int tid = threadIdx.x;
  const int wave = tid >> 6, lane = tid & 63;
  // XCD-chunked swizzle: 2048 wgs, 8 XCDs, 256 per XCD (bijective: 2048%8==0)
  const int wg = (blockIdx.x & 7) * 256 + (blockIdx.x >> 3);
  const int bm = wg >> 2, bn = wg & 3;             // 512 row-tiles x 4 col-tiles
  const int wm = wave >> 1, wn = wave & 1;         // 2x2 wave grid, 64x64/wave
  const long arow0 = (long)bm * 128;
  const int brow0 = bn * 128;

  f32x16 acc_hh[2][2] = {};
  f32x16 acc_mx[2][2] = {};

  // Stage K-step kt into buffer `dst`. LDS dest linear (wave-uniform base,
  // HW adds lane*16); source carries lane offset + XOR swizzle (involution).
#define STAGE(dst, kt)                                                        \
  {                                                                           \
    char* db = lds + (dst) * 32768 + wave * 1024;                             \
    const int kb2 = (kt) * 64;                                                \
    _Pragma("unroll")                                                         \
    for (int pass = 0; pass < 2; ++pass) {                                    \
      int p = pass * 4096 + wave * 1024 + lane * 16;                          \
      int row = p >> 6;          /* 64-B rows: [128][32] f16 */               \
      int q = p ^ (((row >> 1) & 3) << 4);                                    \
      int cbyt = q & 63;                                                      \
      long ao = (arow0 + row) * 1024 + kb2 + cbyt;                            \
      long bo = (long)(brow0 + row) * 1024 + kb2 + cbyt;                      \
      gload16((const char*)AHi + ao, db + pass * 4096);                       \
      gload16((const char*)ALo + ao, db + 8192 + pass * 4096);                \
      gload16((const char*)BHi + bo, db + 16384 + pass * 4096);               \
      gload16((const char*)BLo + bo, db + 24576 + pass * 4096);               \
    }                                                                         \
  }

  STAGE(0, 0);
  __syncthreads();

  for (int kt = 0; kt < 16; ++kt) {
    const int cur = kt & 1;
    if (kt < 15) STAGE(cur ^ 1, kt + 1);           // prefetch next K-step

    const char* bufp = lds + cur * 32768;
    h16x8 ah[2][2], al[2][2], bh[2][2], bl[2][2];  // [ks][i or j]
#pragma unroll
    for (int ks = 0; ks < 2; ++ks) {
#pragma unroll
      for (int i = 0; i < 2; ++i) {
        int ra = wm * 64 + i * 32 + (lane & 31);
        int offa = (ra * 64 + ks * 32 + ((lane >> 5) << 4)) ^ (((ra >> 1) & 3) << 4);
        ah[ks][i] = *(const h16x8*)(bufp + offa);
        al[ks][i] = *(const h16x8*)(bufp + 8192 + offa);
        int rb = wn * 64 + i * 32 + (lane & 31);
        int offb = (rb * 64 + ks * 32 + ((lane >> 5) << 4)) ^ (((rb >> 1) & 3) << 4);
        bh[ks][i] = *(const h16x8*)(bufp + 16384 + offb);
        bl[ks][i] = *(const h16x8*)(bufp + 24576 + offb);
      }
    }
    // hh block, then hl, then lh: dependent same-acc MFMAs spaced by 4+.
#pragma unroll
    for (int ks = 0; ks < 2; ++ks)
#pragma unroll
      for (int i = 0; i < 2; ++i)
#pragma unroll
        for (int j = 0; j < 2; ++j)
          acc_hh[i][j] = __builtin_amdgcn_mfma_f32_32x32x16_f16(ah[ks][i], bh[ks][j], acc_hh[i][j], 0, 0, 0);
#pragma unroll
    for (int ks = 0; ks < 2; ++ks)
#pragma unroll
      for (int i = 0; i < 2; ++i)
#pragma unroll
        for (int j = 0; j < 2; ++j)
          acc_mx[i][j] = __builtin_amdgcn_mfma_f32_32x32x16_f16(ah[ks][i], bl[ks][j], acc_mx[i][j], 0, 0, 0);
#pragma unroll
    for (int ks = 0; ks < 2; ++ks)
#pragma unroll
      for (int i = 0; i < 2; ++i)
#pragma unroll
        for (int j = 0; j < 2; ++j)
          acc_mx[i][j] = __builtin_amdgcn_mfma_f32_32x32x16_f16(al[ks][i], bh[ks][j], acc_mx[i][j], 0, 0, 0);
    __syncthreads();
  }
#undef STAGE

  // C/D layout (32x32, m74/m101): col = lane&31, row = (r&3)+8*(r>>2)+4*(lane>>5)
  if (EPI == 1) {
#pragma unroll
    for (int j = 0; j < 2; ++j) {
      int colg = bn * 128 + wn * 64 + j * 32 + (lane & 31);
      float bv = bias[colg];
#pragma unroll
      for (int i = 0; i < 2; ++i)
#pragma unroll
        for (int r = 0; r < 16; ++r) {
          long row = arow0 + wm * 64 + i * 32 + (r & 3) + 8 * (r >> 2) + 4 * (lane >> 5);
          Cf32[row * NDIM + colg] = acc_hh[i][j][r] + acc_mx[i][j][r] * LO_INV + bv;
        }
    }
  } else {
    // pack relu(v) as (hi | lo<<16) u32 into LDS [128][128], then coalesced
    // dual-plane 8-B stores.
#pragma unroll
    for (int j = 0; j < 2; ++j) {
      int lcol = wn * 64 + j * 32 + (lane & 31);
      float bv = bias[bn * 128 + lcol];
#pragma unroll
      for (int i = 0; i < 2; ++i)
#pragma unroll
        for (int r = 0; r < 16; ++r) {
          int lrow = wm * 64 + i * 32 + (r & 3) + 8 * (r >> 2) + 4 * (lane >> 5);
          float v = fmaxf(acc_hh[i][j][r] + acc_mx[i][j][r] * LO_INV + bv, 0.0f);
          h16 h = (h16)v;
          h16 l = (h16)((v - (float)h) * LO_SCALE);
          unsigned uu = (unsigned)__builtin_bit_cast(unsigned short, h) |
                        ((unsigned)__builtin_bit_cast(unsigned short, l) << 16);
          *(unsigned*)(lds + lrow * 512 + lcol * 4) = uu;
        }
    }
    __syncthreads();
#pragma unroll
    for (int pass = 0; pass < 16; ++pass) {
      int o = (pass * 256 + tid) * 16;
      int lrow = o >> 9;                           // 512-B packed rows
      int lcb = o & 511;                           // u32-col byte offset
      uint4 d = *(const uint4*)(lds + o);
      uint2 hi, lo;
      hi.x = (d.x & 0xffffu) | (d.y << 16);
      hi.y = (d.z & 0xffffu) | (d.w << 16);
      lo.x = (d.x >> 16) | (d.y & 0xffff0000u);
      lo.y = (d.z >> 16) | (d.w & 0xffff0000u);
      long gb = (arow0 + lrow) * 1024 + bn * 256 + (lcb >> 1);
      *(uint2*)((char*)OHi + gb) = hi;
      *(uint2*)((char*)OLo + gb) = lo;
    }
  }
}

// ---- fallback GEMM (on-the-fly f32 split), only used if ws too small ----
__launch_bounds__(256, 2)
__global__ void gemm_fb(const float* __restrict__ Af32,
                        const h16* __restrict__ BHi, const h16* __restrict__ BLo,
                        const float* __restrict__ bias,
                        h16* __restrict__ OHi, h16* __restrict__ OLo) {
  __shared__ __align__(16) char lds[65536];
  const int tid = threadIdx.x;
  const int wave = tid >> 6, lane = tid & 63;
  const int bm = blockIdx.x >> 2, bn = blockIdx.x & 3;
  const int wm = wave >> 1, wn = wave & 1;
  const long arow0 = (long)bm * 128;
  const int brow0 = bn * 128;
  f32x4 acc_hh[4][4] = {};
  f32x4 acc_mx[4][4] = {};
  for (int kt = 0; kt < 8; ++kt) {
    const int kb = kt * 64;
#pragma unroll
    for (int pass = 0; pass < 8; ++pass) {
      int wb = pass * 4096 + wave * 1024;
      int p = wb + lane * 16;
      int row = p >> 8;
      int q = p ^ ((row & 15) << 4);
      long off = ((arow0 + row) * KDIM + kb) * 4 + (q & 255);
      gload16((const char*)Af32 + off, lds + wb);
    }
#pragma unroll
    for (int pass = 0; pass < 4; ++pass) {
      int wb = pass * 4096 + wave * 1024;
      int p = wb + lane * 16;
      int row = p >> 7;
      int q = p ^ ((row & 7) << 4);
      long off = ((long)(brow0 + row) * KDIM + kb) * 2 + (q & 127);
      gload16((const char*)BHi + off, lds + 32768 + wb);
      gload16((const char*)BLo + off, lds + 49152 + wb);
    }
    __syncthreads();
#pragma unroll
    for (int ks = 0; ks < 2; ++ks) {
      const int k0 = ks * 32 + (lane >> 4) * 8;
      h16x8 ah[4], al[4], bh[4], bl[4];
#pragma unroll
      for (int i = 0; i < 4; ++i) {
        int row = wm * 64 + i * 16 + (lane & 15);
        int b0 = (row * 256 + k0 * 4) ^ ((row & 15) << 4);
        int b1 = (row * 256 + k0 * 4 + 16) ^ ((row & 15) << 4);
        f32x4 u0 = *(const f32x4*)(lds + b0);
        f32x4 u1 = *(const f32x4*)(lds + b1);
#pragma unroll
        for (int t = 0; t < 4; ++t) {
          h16 h = (h16)u0[t];
          ah[i][t] = h; al[i][t] = (h16)((u0[t] - (float)h) * LO_SCALE);
        }
#pragma unroll
        for (int t = 0; t < 4; ++t) {
          h16 h = (h16)u1[t];
          ah[i][4 + t] = h; al[i][4 + t] = (h16)((u1[t] - (float)h) * LO_SCALE);
        }
      }
#pragma unroll
      for (int j = 0; j < 4; ++j) {
        int row = wn * 64 + j * 16 + (lane & 15);
        int byt = (row * 128 + k0 * 2) ^ ((row & 7) << 4);
        bh[j] = *(const h16x8*)(lds + 32768 + byt);
        bl[j] = *(const h16x8*)(lds + 49152 + byt);
      }
#pragma unroll
      for (int i = 0; i < 4; ++i)
#pragma unroll
        for (int j = 0; j < 4; ++j) {
          acc_hh[i][j] = __builtin_amdgcn_mfma_f32_16x16x32_f16(ah[i], bh[j], acc_hh[i][j], 0, 0, 0);
          acc_mx[i][j] = __builtin_amdgcn_mfma_f32_16x16x32_f16(ah[i], bl[j], acc_mx[i][j], 0, 0, 0);
          acc_mx[i][j] = __builtin_amdgcn_mfma_f32_16x16x32_f16(al[i], bh[j], acc_mx[i][j], 0, 0, 0);
        }
    }
    __syncthreads();
  }
#pragma unroll
  for (int j = 0; j < 4; ++j) {
    int col = bn * 128 + wn * 64 + j * 16 + (lane & 15);
    float bv = bias[col];
#pragma unroll
    for (int i = 0; i < 4; ++i) {
      long row = arow0 + wm * 64 + i * 16 + ((lane >> 4) * 4);
#pragma unroll
      for (int r = 0; r < 4; ++r) {
        float v = fmaxf(acc_hh[i][j][r] + acc_mx[i][j][r] * LO_INV + bv, 0.0f);
        long idx = (row + r) * (long)NDIM + col;
        h16 h = (h16)v;
        OHi[idx] = h;
        OLo[idx] = (h16)((v - (float)h) * LO_SCALE);
      }
    }
  }
}

// ---------------- K3: gumbel + argmax + codebook gather ----------------
__global__ void k3_argmax_gather(const float* __restrict__ logits,
                                 const float* __restrict__ u,
                                 const float* __restrict__ cb,
                                 const int* __restrict__ testing,
                                 float* __restrict__ codes) {
  const int wave = threadIdx.x >> 6, lane = threadIdx.x & 63;
  const long row = (long)blockIdx.x * 4 + wave;    // one wave per row
  const f32x4* lrow = (const f32x4*)(logits + row * 512);
  const f32x4* urow = (const f32x4*)(u + row * 512);
  const int test = *testing;

  float best = -3.4e38f;
  int bi = 0;
#pragma unroll
  for (int h = 0; h < 2; ++h) {
    int c4 = h * 64 + lane;
    f32x4 z = lrow[c4];
    if (!test) {
      f32x4 uu = urow[c4];
#pragma unroll
      for (int t = 0; t < 4; ++t)
        z[t] += -logf(-logf(uu[t] + 1e-20f) + 1e-20f);
    }
#pragma unroll
    for (int t = 0; t < 4; ++t) {                  // in-lane ascending indices
      int c = c4 * 4 + t;
      if (z[t] > best) { best = z[t]; bi = c; }
    }
  }
#pragma unroll
  for (int off = 32; off; off >>= 1) {             // max with min-index ties
    float ob = __shfl_xor(best, off);
    int oi = __shfl_xor(bi, off);
    if (ob > best || (ob == best && oi < bi)) { best = ob; bi = oi; }
  }
  const f32x4* src = (const f32x4*)(cb + (long)bi * 512);
  f32x4* dst = (f32x4*)(codes + row * 512);
  dst[lane] = src[lane];
  dst[lane + 64] = src[lane + 64];
}

// ---------------- host ----------------
extern "C" void kernel_launch(void* const* d_in, const int* in_sizes, int n_in,
                              void* d_out, int out_size, void* d_ws, size_t ws_size,
                              hipStream_t stream) {
  const float* X = (const float*)d_in[0];
  const float* Wh = (const float*)d_in[1];
  const float* bh = (const float*)d_in[2];
  const float* Wl = (const float*)d_in[3];
  const float* bl = (const float*)d_in[4];
  const float* cb = (const float*)d_in[5];
  const float* u = (const float*)d_in[6];
  const int* testing = (const int*)d_in[7];

  float* logits = (float*)d_out;                   // 33554432 f32
  float* codes = logits + 33554432;                // 33554432 f32
  // hiddens hi/lo f16 planes live in the codes region until K3 overwrites it
  h16* Hhi = (h16*)codes;
  h16* Hlo = Hhi + 33554432;

  h16* WhHi = (h16*)d_ws;                          // 4 x 0.5 MB weight planes
  h16* WhLo = WhHi + 262144;
  h16* WlHi = WhLo + 262144;
  h16* WlLo = WlHi + 262144;
  h16* Xhi = (h16*)((char*)d_ws + 2097152);        // 134 MB X planes
  h16* Xlo = Xhi + 33554432;
  const bool presplit = ws_size >= (size_t)2097152 + (size_t)134217728;

  split_w<<<dim3(1024), dim3(256), 0, stream>>>(Wh, Wl, WhHi, WhLo, WlHi, WlLo);

  if (presplit) {
    split_x<<<dim3(32768), dim3(256), 0, stream>>>((const f32x4*)X, (h16x4*)Xhi, (h16x4*)Xlo);
    gemm2_k<0><<<dim3(2048), dim3(256), 0, stream>>>(Xhi, Xlo, WhHi, WhLo, bh,
                                                     nullptr, Hhi, Hlo);
  } else {
    gemm_fb<<<dim3(2048), dim3(256), 0, stream>>>(X, WhHi, WhLo, bh, Hhi, Hlo);
  }
  gemm2_k<1><<<dim3(2048), dim3(256), 0, stream>>>(Hhi, Hlo, WlHi, WlLo, bl,
                                                   logits, nullptr, nullptr);

  k3_argmax_gather<<<dim3(16384), dim3(256), 0, stream>>>(logits, u, cb, testing, codes);
}